// Round 8
// baseline (119.554 us; speedup 1.0000x reference)
//
#include <hip/hip_runtime.h>

#define N 8000
#define SEQ 200
#define MAX_STEPS 199

#define REG_BLOCKS 2048
#define REG_THREADS 256
#define HALF_BLOCKS 1024
#define SIDE_T (HALF_BLOCKS * REG_THREADS)   // 262144 threads per matrix
#define NN4 16000000                         // N*N/4 float4 per matrix
#define FULL_STRIDES 61                      // 61*262144 = 15,990,784; tail 9216

typedef float f4 __attribute__((ext_vector_type(4)));

__device__ __forceinline__ float log_sum4(f4 v) {
    // log(|x|+1) = ln2 * log2(|x|+1); ln2*0.5 folded into the final atomic.
    return __log2f(fabsf(v[0]) + 1.0f) + __log2f(fabsf(v[1]) + 1.0f) +
           __log2f(fabsf(v[2]) + 1.0f) + __log2f(fabsf(v[3]) + 1.0f);
}

// -------------------------------------------------------------------------
// K1: zero out; gather D[t][i] = s_t*pe[a_t][a_i] + (1-s_t)*ne[a_t][a_i]
//     into workspace. 39601 threads over 155 blocks -> scatter is parallel.
// -------------------------------------------------------------------------
__global__ void k_init_gather(const int* __restrict__ a,
                              const float* __restrict__ s,
                              const float* __restrict__ pe,
                              const float* __restrict__ ne,
                              float* __restrict__ D, int useD,
                              float* __restrict__ out) {
    if (blockIdx.x == 0 && threadIdx.x == 0) out[0] = 0.0f;
    if (!useD) return;

    __shared__ int   sa[MAX_STEPS];
    __shared__ float ss[MAX_STEPS];
    for (int i = threadIdx.x; i < MAX_STEPS; i += blockDim.x) {
        sa[i] = a[i];
        ss[i] = s[i];
    }
    __syncthreads();

    int idx = blockIdx.x * blockDim.x + threadIdx.x;
    const int total = MAX_STEPS * MAX_STEPS;
    if (idx < total) {
        int t = idx / MAX_STEPS;
        int i = idx - t * MAX_STEPS;
        float st = ss[t];
        size_t off = (size_t)sa[t] * N + (size_t)sa[i];
        float d = st * pe[off] + (1.0f - st) * ne[off];
        D[idx] = d;
    }
}

// -------------------------------------------------------------------------
// K2: regularizer. NT loads on both matrices (R6, kept). NEW: one matrix
//     per block half -> each wave emits a single monotone address stream
//     (no alternation between two regions 256 MB apart). unroll 4 keeps
//     4 loads in flight, matching R6's depth.
// -------------------------------------------------------------------------
__global__ void __launch_bounds__(REG_THREADS)
k_reg(const float* __restrict__ pe,
      const float* __restrict__ ne,
      float* __restrict__ out) {
    const bool is_ne = (blockIdx.x >= HALF_BLOCKS);
    const f4* __restrict__ src = (const f4*)(is_ne ? ne : pe);
    const int rt =
        (int)(blockIdx.x - (is_ne ? HALF_BLOCKS : 0)) * REG_THREADS + threadIdx.x;

    float acc = 0.0f;
    #pragma unroll 4
    for (int k = 0; k < FULL_STRIDES; ++k) {
        size_t p = (size_t)rt + (size_t)k * SIDE_T;
        f4 v = __builtin_nontemporal_load(&src[p]);
        acc += log_sum4(v);
    }
    // tail stride (rt < 9216)
    {
        size_t p = (size_t)rt + (size_t)FULL_STRIDES * SIDE_T;
        if (p < (size_t)NN4) {
            f4 v = __builtin_nontemporal_load(&src[p]);
            acc += log_sum4(v);
        }
    }

    // wave64 reduce
    #pragma unroll
    for (int o = 32; o > 0; o >>= 1) acc += __shfl_down(acc, o);
    __shared__ float wsum[REG_THREADS / 64];
    int lane = threadIdx.x & 63;
    int wid  = threadIdx.x >> 6;
    if (lane == 0) wsum[wid] = acc;
    __syncthreads();
    if (threadIdx.x == 0) {
        float b = 0.0f;
        #pragma unroll
        for (int w = 0; w < REG_THREADS / 64; ++w) b += wsum[w];
        // 0.5 * ln(2) folded here (log2 -> ln conversion)
        atomicAdd(out, 0.34657359027997264f * b);
    }
}

// -------------------------------------------------------------------------
// K3: sequential loss from D (coalesced columns, cache-resident). 1 block.
// -------------------------------------------------------------------------
__global__ void k_loss(const int* __restrict__ a,
                       const float* __restrict__ s,
                       const float* __restrict__ pe,
                       const float* __restrict__ ne,
                       const float* __restrict__ kp,
                       const float* __restrict__ D, int useD,
                       float* __restrict__ out) {
    __shared__ int   sa[MAX_STEPS];
    __shared__ float ss[MAX_STEPS];
    int tid = threadIdx.x;
    for (int i = tid; i < MAX_STEPS; i += blockDim.x) {
        sa[i] = a[i];
        ss[i] = s[i];
    }
    __syncthreads();

    __shared__ int V;
    if (tid == 0) {
        int v = MAX_STEPS;
        for (int t = 0; t < MAX_STEPS; ++t) {
            if (ss[t] < 0.0f) { v = t; break; }
        }
        V = v;
    }
    __syncthreads();

    float li = 0.0f;
    if (tid < MAX_STEPS && tid < V) {
        int j = sa[tid];
        float k = kp[j];
        if (useD) {
            int t = 0;
            for (; t + 8 <= tid; t += 8) {
                float d[8];
                #pragma unroll
                for (int u = 0; u < 8; ++u) d[u] = D[(t + u) * MAX_STEPS + tid];
                #pragma unroll
                for (int u = 0; u < 8; ++u)
                    k = fminf(fmaxf(k + d[u], -30.0f), 30.0f);
            }
            for (; t < tid; ++t) {
                float d = D[t * MAX_STEPS + tid];
                k = fminf(fmaxf(k + d, -30.0f), 30.0f);
            }
        } else {
            for (int t = 0; t < tid; ++t) {
                float st = ss[t];
                size_t off = (size_t)sa[t] * N + (size_t)j;
                float d = st * pe[off] + (1.0f - st) * ne[off];
                k = fminf(fmaxf(k + d, -30.0f), 30.0f);
            }
        }
        float p = fminf(fmaxf(k, 0.01f), 0.99f);
        li = -(ss[tid] * logf(p) + (1.0f - ss[tid]) * logf(1.0f - p));
    }

    #pragma unroll
    for (int o = 32; o > 0; o >>= 1) li += __shfl_down(li, o);
    __shared__ float wsum[4];
    int lane = tid & 63;
    int wid  = tid >> 6;
    if (lane == 0) wsum[wid] = li;
    __syncthreads();
    if (tid == 0) {
        float total = wsum[0] + wsum[1] + wsum[2] + wsum[3];
        atomicAdd(out, total);
    }
}

extern "C" void kernel_launch(void* const* d_in, const int* in_sizes, int n_in,
                              void* d_out, int out_size, void* d_ws, size_t ws_size,
                              hipStream_t stream) {
    const int*   a  = (const int*)d_in[0];
    const float* s  = (const float*)d_in[1];
    const float* pe = (const float*)d_in[2];
    const float* ne = (const float*)d_in[3];
    const float* kp = (const float*)d_in[4];
    float* out = (float*)d_out;

    float* D = (float*)d_ws;
    int useD = (ws_size >= sizeof(float) * MAX_STEPS * MAX_STEPS) ? 1 : 0;

    const int gatherBlocks = (MAX_STEPS * MAX_STEPS + 255) / 256;
    k_init_gather<<<gatherBlocks, 256, 0, stream>>>(a, s, pe, ne, D, useD, out);
    k_reg<<<REG_BLOCKS, REG_THREADS, 0, stream>>>(pe, ne, out);
    k_loss<<<1, 256, 0, stream>>>(a, s, pe, ne, kp, D, useD, out);
}

// Round 9
// 105.045 us; speedup vs baseline: 1.1381x; 1.1381x over previous
//
#include <hip/hip_runtime.h>

#define N 8000
#define SEQ 200
#define MAX_STEPS 199

#define REG_THREADS 256
#define SB 1280                         // streaming blocks (NT loads)
#define CB 768                          // cached blocks (L3-resident slice)
#define ST (SB * REG_THREADS)           // 327680 streaming threads
#define CT (CB * REG_THREADS)           // 196608 cached threads
#define NN4 16000000                    // f4 per matrix
#define S1 10003456                     // streamed f4 per matrix (first part)
// cached region per matrix: [S1, 16M) = 5,996,544 f4 (~96 MB); both matrices ~192 MB
#define SFULL 30                        // 30*327680 = 9,830,400; tail 173,056
#define CFULL 30                        // 30*196608 = 5,898,240; tail  98,304

typedef float f4 __attribute__((ext_vector_type(4)));

__device__ __forceinline__ float log_sum4(f4 v) {
    // log(|x|+1) = ln2 * log2(|x|+1); ln2*0.5 folded into the final atomic.
    return __log2f(fabsf(v[0]) + 1.0f) + __log2f(fabsf(v[1]) + 1.0f) +
           __log2f(fabsf(v[2]) + 1.0f) + __log2f(fabsf(v[3]) + 1.0f);
}

// -------------------------------------------------------------------------
// K1: zero out; gather D[t][i] into workspace (parallel scatter, 155 blocks).
// -------------------------------------------------------------------------
__global__ void k_init_gather(const int* __restrict__ a,
                              const float* __restrict__ s,
                              const float* __restrict__ pe,
                              const float* __restrict__ ne,
                              float* __restrict__ D, int useD,
                              float* __restrict__ out) {
    if (blockIdx.x == 0 && threadIdx.x == 0) out[0] = 0.0f;
    if (!useD) return;

    __shared__ int   sa[MAX_STEPS];
    __shared__ float ss[MAX_STEPS];
    for (int i = threadIdx.x; i < MAX_STEPS; i += blockDim.x) {
        sa[i] = a[i];
        ss[i] = s[i];
    }
    __syncthreads();

    int idx = blockIdx.x * blockDim.x + threadIdx.x;
    const int total = MAX_STEPS * MAX_STEPS;
    if (idx < total) {
        int t = idx / MAX_STEPS;
        int i = idx - t * MAX_STEPS;
        float st = ss[t];
        size_t off = (size_t)sa[t] * N + (size_t)sa[i];
        float d = st * pe[off] + (1.0f - st) * ne[off];
        D[idx] = d;
    }
}

// -------------------------------------------------------------------------
// K2: regularizer, HBM/L3 split.
//   blocks [0, SB):   NT dual-stream sweep of pe4/ne4 [0, S1)   -> HBM
//   blocks [SB, SB+CB): cached dual-stream sweep of [S1, 16M)   -> L3-resident
//   The cached slice (~192 MB) fits in the 256 MB Infinity Cache and is
//   never evicted by the NT stream (NT doesn't allocate), so on graph
//   replays it is served from L3 concurrently with the HBM stream.
// -------------------------------------------------------------------------
__global__ void __launch_bounds__(REG_THREADS)
k_reg(const float* __restrict__ pe,
      const float* __restrict__ ne,
      float* __restrict__ out) {
    const f4* __restrict__ pe4 = (const f4*)pe;
    const f4* __restrict__ ne4 = (const f4*)ne;

    float acc = 0.0f;

    if (blockIdx.x < SB) {
        // ---------------- streaming half (NT, R6-exact shape) --------------
        const int rt = (int)blockIdx.x * REG_THREADS + threadIdx.x;
        #pragma unroll 2
        for (int k = 0; k < SFULL; ++k) {
            size_t p = (size_t)rt + (size_t)k * ST;
            f4 v = __builtin_nontemporal_load(&pe4[p]);
            f4 w = __builtin_nontemporal_load(&ne4[p]);
            acc += log_sum4(v);
            acc += log_sum4(w);
        }
        {   // tail: rt < 173,056
            size_t p = (size_t)rt + (size_t)SFULL * ST;
            if (p < (size_t)S1) {
                f4 v = __builtin_nontemporal_load(&pe4[p]);
                f4 w = __builtin_nontemporal_load(&ne4[p]);
                acc += log_sum4(v);
                acc += log_sum4(w);
            }
        }
    } else {
        // ---------------- cached half (L3-resident slice) ------------------
        const int rt = (int)(blockIdx.x - SB) * REG_THREADS + threadIdx.x;
        #pragma unroll 2
        for (int k = 0; k < CFULL; ++k) {
            size_t p = (size_t)S1 + (size_t)rt + (size_t)k * CT;
            f4 v = pe4[p];
            f4 w = ne4[p];
            acc += log_sum4(v);
            acc += log_sum4(w);
        }
        {   // tail: rt < 98,304
            size_t p = (size_t)S1 + (size_t)rt + (size_t)CFULL * CT;
            if (p < (size_t)NN4) {
                f4 v = pe4[p];
                f4 w = ne4[p];
                acc += log_sum4(v);
                acc += log_sum4(w);
            }
        }
    }

    // wave64 reduce
    #pragma unroll
    for (int o = 32; o > 0; o >>= 1) acc += __shfl_down(acc, o);
    __shared__ float wsum[REG_THREADS / 64];
    int lane = threadIdx.x & 63;
    int wid  = threadIdx.x >> 6;
    if (lane == 0) wsum[wid] = acc;
    __syncthreads();
    if (threadIdx.x == 0) {
        float b = 0.0f;
        #pragma unroll
        for (int w = 0; w < REG_THREADS / 64; ++w) b += wsum[w];
        // 0.5 * ln(2) folded here (log2 -> ln conversion)
        atomicAdd(out, 0.34657359027997264f * b);
    }
}

// -------------------------------------------------------------------------
// K3: sequential loss from D (coalesced columns, cache-resident). 1 block.
// -------------------------------------------------------------------------
__global__ void k_loss(const int* __restrict__ a,
                       const float* __restrict__ s,
                       const float* __restrict__ pe,
                       const float* __restrict__ ne,
                       const float* __restrict__ kp,
                       const float* __restrict__ D, int useD,
                       float* __restrict__ out) {
    __shared__ int   sa[MAX_STEPS];
    __shared__ float ss[MAX_STEPS];
    int tid = threadIdx.x;
    for (int i = tid; i < MAX_STEPS; i += blockDim.x) {
        sa[i] = a[i];
        ss[i] = s[i];
    }
    __syncthreads();

    __shared__ int V;
    if (tid == 0) {
        int v = MAX_STEPS;
        for (int t = 0; t < MAX_STEPS; ++t) {
            if (ss[t] < 0.0f) { v = t; break; }
        }
        V = v;
    }
    __syncthreads();

    float li = 0.0f;
    if (tid < MAX_STEPS && tid < V) {
        int j = sa[tid];
        float k = kp[j];
        if (useD) {
            int t = 0;
            for (; t + 8 <= tid; t += 8) {
                float d[8];
                #pragma unroll
                for (int u = 0; u < 8; ++u) d[u] = D[(t + u) * MAX_STEPS + tid];
                #pragma unroll
                for (int u = 0; u < 8; ++u)
                    k = fminf(fmaxf(k + d[u], -30.0f), 30.0f);
            }
            for (; t < tid; ++t) {
                float d = D[t * MAX_STEPS + tid];
                k = fminf(fmaxf(k + d, -30.0f), 30.0f);
            }
        } else {
            for (int t = 0; t < tid; ++t) {
                float st = ss[t];
                size_t off = (size_t)sa[t] * N + (size_t)j;
                float d = st * pe[off] + (1.0f - st) * ne[off];
                k = fminf(fmaxf(k + d, -30.0f), 30.0f);
            }
        }
        float p = fminf(fmaxf(k, 0.01f), 0.99f);
        li = -(ss[tid] * logf(p) + (1.0f - ss[tid]) * logf(1.0f - p));
    }

    #pragma unroll
    for (int o = 32; o > 0; o >>= 1) li += __shfl_down(li, o);
    __shared__ float wsum[4];
    int lane = tid & 63;
    int wid  = tid >> 6;
    if (lane == 0) wsum[wid] = li;
    __syncthreads();
    if (tid == 0) {
        float total = wsum[0] + wsum[1] + wsum[2] + wsum[3];
        atomicAdd(out, total);
    }
}

extern "C" void kernel_launch(void* const* d_in, const int* in_sizes, int n_in,
                              void* d_out, int out_size, void* d_ws, size_t ws_size,
                              hipStream_t stream) {
    const int*   a  = (const int*)d_in[0];
    const float* s  = (const float*)d_in[1];
    const float* pe = (const float*)d_in[2];
    const float* ne = (const float*)d_in[3];
    const float* kp = (const float*)d_in[4];
    float* out = (float*)d_out;

    float* D = (float*)d_ws;
    int useD = (ws_size >= sizeof(float) * MAX_STEPS * MAX_STEPS) ? 1 : 0;

    const int gatherBlocks = (MAX_STEPS * MAX_STEPS + 255) / 256;
    k_init_gather<<<gatherBlocks, 256, 0, stream>>>(a, s, pe, ne, D, useD, out);
    k_reg<<<SB + CB, REG_THREADS, 0, stream>>>(pe, ne, out);
    k_loss<<<1, 256, 0, stream>>>(a, s, pe, ne, kp, D, useD, out);
}

// Round 10
// 104.664 us; speedup vs baseline: 1.1423x; 1.0036x over previous
//
#include <hip/hip_runtime.h>

#define N 8000
#define SEQ 200
#define MAX_STEPS 199

#define REG_THREADS 256
#define SB 1472                         // streaming blocks (NT loads)
#define CB 576                          // cached blocks (L3-resident slice)
#define ST (SB * REG_THREADS)           // 376,832 streaming threads
#define CT (CB * REG_THREADS)           // 147,456 cached threads
#define NN4 16000000                    // f4 per matrix
#define S1 11520000                     // streamed f4 per matrix (first ~184 MB)
// cached region per matrix: [S1, 16M) = 4,480,000 f4 (~72 MB); both ~143 MB
#define SFULL 30                        // 30*376,832 = 11,304,960; tail 215,040
#define CFULL 30                        // 30*147,456 =  4,423,680; tail  56,320

typedef float f4 __attribute__((ext_vector_type(4)));

__device__ __forceinline__ float log_sum4(f4 v) {
    // log(|x|+1) = ln2 * log2(|x|+1); ln2*0.5 folded into the final atomic.
    return __log2f(fabsf(v[0]) + 1.0f) + __log2f(fabsf(v[1]) + 1.0f) +
           __log2f(fabsf(v[2]) + 1.0f) + __log2f(fabsf(v[3]) + 1.0f);
}

// -------------------------------------------------------------------------
// K1: zero out; gather D[t][i] into workspace (parallel scatter, 155 blocks).
// -------------------------------------------------------------------------
__global__ void k_init_gather(const int* __restrict__ a,
                              const float* __restrict__ s,
                              const float* __restrict__ pe,
                              const float* __restrict__ ne,
                              float* __restrict__ D, int useD,
                              float* __restrict__ out) {
    if (blockIdx.x == 0 && threadIdx.x == 0) out[0] = 0.0f;
    if (!useD) return;

    __shared__ int   sa[MAX_STEPS];
    __shared__ float ss[MAX_STEPS];
    for (int i = threadIdx.x; i < MAX_STEPS; i += blockDim.x) {
        sa[i] = a[i];
        ss[i] = s[i];
    }
    __syncthreads();

    int idx = blockIdx.x * blockDim.x + threadIdx.x;
    const int total = MAX_STEPS * MAX_STEPS;
    if (idx < total) {
        int t = idx / MAX_STEPS;
        int i = idx - t * MAX_STEPS;
        float st = ss[t];
        size_t off = (size_t)sa[t] * N + (size_t)sa[i];
        float d = st * pe[off] + (1.0f - st) * ne[off];
        D[idx] = d;
    }
}

// -------------------------------------------------------------------------
// K2: regularizer, HBM/L3 split rebalanced to measured bandwidths
//     (HBM ~5.1 TB/s, L3-hit path ~2.1 TB/s from R9):
//   blocks [0, SB):    NT dual-stream sweep of pe4/ne4 [0, S1)    -> HBM 368 MB
//   blocks [SB,SB+CB): cached dual-stream sweep of [S1, 16M)      -> L3 ~143 MB
//   Cached slice fits L3 with headroom; NT stream doesn't allocate, so the
//   slice stays resident across graph replays.
// -------------------------------------------------------------------------
__global__ void __launch_bounds__(REG_THREADS)
k_reg(const float* __restrict__ pe,
      const float* __restrict__ ne,
      float* __restrict__ out) {
    const f4* __restrict__ pe4 = (const f4*)pe;
    const f4* __restrict__ ne4 = (const f4*)ne;

    float acc = 0.0f;

    if (blockIdx.x < SB) {
        // ---------------- streaming half (NT, R6-exact shape) --------------
        const int rt = (int)blockIdx.x * REG_THREADS + threadIdx.x;
        #pragma unroll 2
        for (int k = 0; k < SFULL; ++k) {
            size_t p = (size_t)rt + (size_t)k * ST;
            f4 v = __builtin_nontemporal_load(&pe4[p]);
            f4 w = __builtin_nontemporal_load(&ne4[p]);
            acc += log_sum4(v);
            acc += log_sum4(w);
        }
        {   // tail: rt < 215,040
            size_t p = (size_t)rt + (size_t)SFULL * ST;
            if (p < (size_t)S1) {
                f4 v = __builtin_nontemporal_load(&pe4[p]);
                f4 w = __builtin_nontemporal_load(&ne4[p]);
                acc += log_sum4(v);
                acc += log_sum4(w);
            }
        }
    } else {
        // ---------------- cached half (L3-resident slice) ------------------
        const int rt = (int)(blockIdx.x - SB) * REG_THREADS + threadIdx.x;
        #pragma unroll 2
        for (int k = 0; k < CFULL; ++k) {
            size_t p = (size_t)S1 + (size_t)rt + (size_t)k * CT;
            f4 v = pe4[p];
            f4 w = ne4[p];
            acc += log_sum4(v);
            acc += log_sum4(w);
        }
        {   // tail: rt < 56,320
            size_t p = (size_t)S1 + (size_t)rt + (size_t)CFULL * CT;
            if (p < (size_t)NN4) {
                f4 v = pe4[p];
                f4 w = ne4[p];
                acc += log_sum4(v);
                acc += log_sum4(w);
            }
        }
    }

    // wave64 reduce
    #pragma unroll
    for (int o = 32; o > 0; o >>= 1) acc += __shfl_down(acc, o);
    __shared__ float wsum[REG_THREADS / 64];
    int lane = threadIdx.x & 63;
    int wid  = threadIdx.x >> 6;
    if (lane == 0) wsum[wid] = acc;
    __syncthreads();
    if (threadIdx.x == 0) {
        float b = 0.0f;
        #pragma unroll
        for (int w = 0; w < REG_THREADS / 64; ++w) b += wsum[w];
        // 0.5 * ln(2) folded here (log2 -> ln conversion)
        atomicAdd(out, 0.34657359027997264f * b);
    }
}

// -------------------------------------------------------------------------
// K3: sequential loss from D (coalesced columns, cache-resident). 1 block.
// -------------------------------------------------------------------------
__global__ void k_loss(const int* __restrict__ a,
                       const float* __restrict__ s,
                       const float* __restrict__ pe,
                       const float* __restrict__ ne,
                       const float* __restrict__ kp,
                       const float* __restrict__ D, int useD,
                       float* __restrict__ out) {
    __shared__ int   sa[MAX_STEPS];
    __shared__ float ss[MAX_STEPS];
    int tid = threadIdx.x;
    for (int i = tid; i < MAX_STEPS; i += blockDim.x) {
        sa[i] = a[i];
        ss[i] = s[i];
    }
    __syncthreads();

    __shared__ int V;
    if (tid == 0) {
        int v = MAX_STEPS;
        for (int t = 0; t < MAX_STEPS; ++t) {
            if (ss[t] < 0.0f) { v = t; break; }
        }
        V = v;
    }
    __syncthreads();

    float li = 0.0f;
    if (tid < MAX_STEPS && tid < V) {
        int j = sa[tid];
        float k = kp[j];
        if (useD) {
            int t = 0;
            for (; t + 8 <= tid; t += 8) {
                float d[8];
                #pragma unroll
                for (int u = 0; u < 8; ++u) d[u] = D[(t + u) * MAX_STEPS + tid];
                #pragma unroll
                for (int u = 0; u < 8; ++u)
                    k = fminf(fmaxf(k + d[u], -30.0f), 30.0f);
            }
            for (; t < tid; ++t) {
                float d = D[t * MAX_STEPS + tid];
                k = fminf(fmaxf(k + d, -30.0f), 30.0f);
            }
        } else {
            for (int t = 0; t < tid; ++t) {
                float st = ss[t];
                size_t off = (size_t)sa[t] * N + (size_t)j;
                float d = st * pe[off] + (1.0f - st) * ne[off];
                k = fminf(fmaxf(k + d, -30.0f), 30.0f);
            }
        }
        float p = fminf(fmaxf(k, 0.01f), 0.99f);
        li = -(ss[tid] * logf(p) + (1.0f - ss[tid]) * logf(1.0f - p));
    }

    #pragma unroll
    for (int o = 32; o > 0; o >>= 1) li += __shfl_down(li, o);
    __shared__ float wsum[4];
    int lane = tid & 63;
    int wid  = tid >> 6;
    if (lane == 0) wsum[wid] = li;
    __syncthreads();
    if (tid == 0) {
        float total = wsum[0] + wsum[1] + wsum[2] + wsum[3];
        atomicAdd(out, total);
    }
}

extern "C" void kernel_launch(void* const* d_in, const int* in_sizes, int n_in,
                              void* d_out, int out_size, void* d_ws, size_t ws_size,
                              hipStream_t stream) {
    const int*   a  = (const int*)d_in[0];
    const float* s  = (const float*)d_in[1];
    const float* pe = (const float*)d_in[2];
    const float* ne = (const float*)d_in[3];
    const float* kp = (const float*)d_in[4];
    float* out = (float*)d_out;

    float* D = (float*)d_ws;
    int useD = (ws_size >= sizeof(float) * MAX_STEPS * MAX_STEPS) ? 1 : 0;

    const int gatherBlocks = (MAX_STEPS * MAX_STEPS + 255) / 256;
    k_init_gather<<<gatherBlocks, 256, 0, stream>>>(a, s, pe, ne, D, useD, out);
    k_reg<<<SB + CB, REG_THREADS, 0, stream>>>(pe, ne, out);
    k_loss<<<1, 256, 0, stream>>>(a, s, pe, ne, kp, D, useD, out);
}

// Round 11
// 86.805 us; speedup vs baseline: 1.3773x; 1.2057x over previous
//
#include <hip/hip_runtime.h>

#define N 8000
#define SEQ 200
#define MAX_STEPS 199

#define REG_THREADS 256
#define SB 1472                         // streaming blocks (NT loads)
#define CB 576                          // cached blocks (L3-resident slice)
#define ST (SB * REG_THREADS)           // 376,832 streaming threads
#define CT (CB * REG_THREADS)           // 147,456 cached threads
#define NN4 16000000                    // f4 per matrix
#define S1 11520000                     // streamed f4 per matrix (first ~184 MB)
#define SFULL 30                        // 30*376,832 = 11,304,960; tail 215,040
#define CFULL 30                        // 30*147,456 =  4,423,680; tail  56,320

typedef float f4 __attribute__((ext_vector_type(4)));

__device__ __forceinline__ float log_sum4(f4 v) {
    // log(|x|+1) = ln2 * log2(|x|+1); ln2*0.5 folded into the final atomic.
    return __log2f(fabsf(v[0]) + 1.0f) + __log2f(fabsf(v[1]) + 1.0f) +
           __log2f(fabsf(v[2]) + 1.0f) + __log2f(fabsf(v[3]) + 1.0f);
}

// -------------------------------------------------------------------------
// K1: zero out; gather D[t][i] = s_t*pe[a_t][a_i] + (1-s_t)*ne[a_t][a_i]
//     into workspace (parallel scatter across 155 blocks; ~2 us).
// -------------------------------------------------------------------------
__global__ void k_init_gather(const int* __restrict__ a,
                              const float* __restrict__ s,
                              const float* __restrict__ pe,
                              const float* __restrict__ ne,
                              float* __restrict__ D, int useD,
                              float* __restrict__ out) {
    if (blockIdx.x == 0 && threadIdx.x == 0) out[0] = 0.0f;
    if (!useD) return;

    __shared__ int   sa[MAX_STEPS];
    __shared__ float ss[MAX_STEPS];
    for (int i = threadIdx.x; i < MAX_STEPS; i += blockDim.x) {
        sa[i] = a[i];
        ss[i] = s[i];
    }
    __syncthreads();

    int idx = blockIdx.x * blockDim.x + threadIdx.x;
    const int total = MAX_STEPS * MAX_STEPS;
    if (idx < total) {
        int t = idx / MAX_STEPS;
        int i = idx - t * MAX_STEPS;
        float st = ss[t];
        size_t off = (size_t)sa[t] * N + (size_t)sa[i];
        float d = st * pe[off] + (1.0f - st) * ne[off];
        D[idx] = d;
    }
}

// -------------------------------------------------------------------------
// K2 (fused): block 0 = sequential loss from D (L2-hot, coalesced, ~3 us,
//     hidden under the reg stream). Blocks 1..SB+CB = R10 regularizer:
//     NT dual-stream [0,S1) -> HBM; cached dual-stream [S1,16M) -> L3.
//     Total read path is capped ~5.5 TB/s (R7/R8/R10 probes), so the only
//     remaining win is removing the serialized k_loss dispatch.
// -------------------------------------------------------------------------
__global__ void __launch_bounds__(REG_THREADS)
k_fused(const int* __restrict__ a,
        const float* __restrict__ s,
        const float* __restrict__ pe,
        const float* __restrict__ ne,
        const float* __restrict__ kp,
        const float* __restrict__ D, int useD,
        float* __restrict__ out) {
    __shared__ float wsum[REG_THREADS / 64];
    const int tid = threadIdx.x;

    if (blockIdx.x == 0) {
        // ---------------- loss block (reads dense D, not pe/ne) ------------
        __shared__ int   sa[MAX_STEPS];
        __shared__ float ss[MAX_STEPS];
        for (int i = tid; i < MAX_STEPS; i += REG_THREADS) {
            sa[i] = a[i];
            ss[i] = s[i];
        }
        __syncthreads();

        __shared__ int V;
        if (tid == 0) {
            int v = MAX_STEPS;
            for (int t = 0; t < MAX_STEPS; ++t)
                if (ss[t] < 0.0f) { v = t; break; }
            V = v;
        }
        __syncthreads();

        float li = 0.0f;
        if (tid < MAX_STEPS && tid < V) {
            int j = sa[tid];
            float k = kp[j];
            if (useD) {
                int t = 0;
                for (; t + 8 <= tid; t += 8) {
                    float d[8];
                    #pragma unroll
                    for (int u = 0; u < 8; ++u) d[u] = D[(t + u) * MAX_STEPS + tid];
                    #pragma unroll
                    for (int u = 0; u < 8; ++u)
                        k = fminf(fmaxf(k + d[u], -30.0f), 30.0f);
                }
                for (; t < tid; ++t) {
                    float d = D[t * MAX_STEPS + tid];
                    k = fminf(fmaxf(k + d, -30.0f), 30.0f);
                }
            } else {
                for (int t = 0; t < tid; ++t) {
                    float st = ss[t];
                    size_t off = (size_t)sa[t] * N + (size_t)j;
                    float d = st * pe[off] + (1.0f - st) * ne[off];
                    k = fminf(fmaxf(k + d, -30.0f), 30.0f);
                }
            }
            float p = fminf(fmaxf(k, 0.01f), 0.99f);
            li = -(ss[tid] * logf(p) + (1.0f - ss[tid]) * logf(1.0f - p));
        }

        #pragma unroll
        for (int o = 32; o > 0; o >>= 1) li += __shfl_down(li, o);
        if ((tid & 63) == 0) wsum[tid >> 6] = li;
        __syncthreads();
        if (tid == 0) {
            float total = 0.0f;
            #pragma unroll
            for (int w = 0; w < REG_THREADS / 64; ++w) total += wsum[w];
            atomicAdd(out, total);
        }
        return;
    }

    // --------------------------- regularizer -------------------------------
    const f4* __restrict__ pe4 = (const f4*)pe;
    const f4* __restrict__ ne4 = (const f4*)ne;
    const int rb = (int)blockIdx.x - 1;

    float acc = 0.0f;

    if (rb < SB) {
        // ---------------- streaming half (NT, R6 shape) --------------------
        const int rt = rb * REG_THREADS + tid;
        #pragma unroll 2
        for (int k = 0; k < SFULL; ++k) {
            size_t p = (size_t)rt + (size_t)k * ST;
            f4 v = __builtin_nontemporal_load(&pe4[p]);
            f4 w = __builtin_nontemporal_load(&ne4[p]);
            acc += log_sum4(v);
            acc += log_sum4(w);
        }
        {   // tail: rt < 215,040
            size_t p = (size_t)rt + (size_t)SFULL * ST;
            if (p < (size_t)S1) {
                f4 v = __builtin_nontemporal_load(&pe4[p]);
                f4 w = __builtin_nontemporal_load(&ne4[p]);
                acc += log_sum4(v);
                acc += log_sum4(w);
            }
        }
    } else {
        // ---------------- cached half (L3-resident slice) ------------------
        const int rt = (rb - SB) * REG_THREADS + tid;
        #pragma unroll 2
        for (int k = 0; k < CFULL; ++k) {
            size_t p = (size_t)S1 + (size_t)rt + (size_t)k * CT;
            f4 v = pe4[p];
            f4 w = ne4[p];
            acc += log_sum4(v);
            acc += log_sum4(w);
        }
        {   // tail: rt < 56,320
            size_t p = (size_t)S1 + (size_t)rt + (size_t)CFULL * CT;
            if (p < (size_t)NN4) {
                f4 v = pe4[p];
                f4 w = ne4[p];
                acc += log_sum4(v);
                acc += log_sum4(w);
            }
        }
    }

    // wave64 reduce
    #pragma unroll
    for (int o = 32; o > 0; o >>= 1) acc += __shfl_down(acc, o);
    if ((tid & 63) == 0) wsum[tid >> 6] = acc;
    __syncthreads();
    if (tid == 0) {
        float b = 0.0f;
        #pragma unroll
        for (int w = 0; w < REG_THREADS / 64; ++w) b += wsum[w];
        // 0.5 * ln(2) folded here (log2 -> ln conversion)
        atomicAdd(out, 0.34657359027997264f * b);
    }
}

extern "C" void kernel_launch(void* const* d_in, const int* in_sizes, int n_in,
                              void* d_out, int out_size, void* d_ws, size_t ws_size,
                              hipStream_t stream) {
    const int*   a  = (const int*)d_in[0];
    const float* s  = (const float*)d_in[1];
    const float* pe = (const float*)d_in[2];
    const float* ne = (const float*)d_in[3];
    const float* kp = (const float*)d_in[4];
    float* out = (float*)d_out;

    float* D = (float*)d_ws;
    int useD = (ws_size >= sizeof(float) * MAX_STEPS * MAX_STEPS) ? 1 : 0;

    const int gatherBlocks = (MAX_STEPS * MAX_STEPS + 255) / 256;
    k_init_gather<<<gatherBlocks, 256, 0, stream>>>(a, s, pe, ne, D, useD, out);
    k_fused<<<SB + CB + 1, REG_THREADS, 0, stream>>>(a, s, pe, ne, kp, D, useD, out);
}